// Round 13
// baseline (144.228 us; speedup 1.0000x reference)
//
#include <hip/hip_runtime.h>
#include <hip/hip_bf16.h>

#define N_NODES 8192
#define E_EDGES 262144
#define DIM 128
#define CAP 128                 // colbuf stride; degree ~ Poisson(32), max << 128
#define LIN_BLOCKS 512          // 16 rows each
#define SCAT_BLOCKS 768
#define NBLK_TOT (LIN_BLOCKS + SCAT_BLOCKS)     // 1280
#define SCAT_THREADS (SCAT_BLOCKS * 256)
#define NZB 32                  // zeroing blocks = first 32 scatter blocks
#define DONE_STRIDE 32          // ints between done slots (128B, own cacheline)
#define FLAG_MAGIC 0x7F3D5B91   // != 0, != 0xAAAAAAAA (poison)

// SINGLE-DISPATCH GCN layer. Everything learned R8-R12 baked in:
//  - NO __threadfence anywhere (fences = buffer_wbl2/inv, 768 blocks
//    invalidating their XCD L2 cost 60-77us in R8-R10).
//  - All cross-block sync via atomic RMWs (performed at the LLC coherence
//    point; immune to non-coherent per-XCD L2s). Proven R11/R12.
//  - Distributed producers (32 blocks zero cursor in parallel; single-block
//    zeroing was RMW-queue-bound, ~15-25us in R11).
//  - Phase-1 outputs (h, colbuf) are written via RETURNING atomicExch so the
//    data itself lives at the LLC; no block plain-reads h/colbuf/cursor in
//    phase 1, so at phase-2 entry no L1/L2 holds any stale line -> plain
//    reads miss to the LLC and see current values. (Atomics don't allocate
//    in read caches -- same property the R12 cursor handshake relied on.)
//  - Phase barrier: per-block vmcnt drain (__syncthreads), atomicAdd(c1,1),
//    throttled RMW-poll c1 >= 1280. All blocks gate on done-slots first so
//    c1/c2 are zeroed (by zeroer block 0, before it signals) ahead of any use
//    -- poison/garbage safe on every call. Last block of phase 2 resets
//    done/c1/c2 for the next graph replay (all polls long since exited).
// Deadlock-safety: zeroers signal BEFORE any wait; 19.5KB LDS, 256 thr =>
// 8 blocks/CU x 256 CUs = 2048 >= 1280 -> co-resident regardless of order;
// __launch_bounds__(256,5) guarantees the >=5 blocks/CU actually needed.
__global__ __launch_bounds__(256, 5) void gcn_mono(
        const int* __restrict__ row, const int* __restrict__ col,
        const float* __restrict__ x, const float* __restrict__ W,
        const float* __restrict__ b,
        int* __restrict__ cursor, int* __restrict__ colbuf,
        __hip_bfloat16* __restrict__ h, float* __restrict__ out,
        int* __restrict__ done) {
    __shared__ union {
        struct { float xsT[32][20]; float wsT[32][132]; } lin;               // 19456 B
        struct { unsigned int bitmap[4][N_NODES / 32];
                 int klist[4][CAP]; float nlist[4][CAP]; } agg;              // 8192 B
    } sm;
    int* c1 = done + NZB * DONE_STRIDE;        // own cacheline
    int* c2 = c1 + 32;                         // own cacheline
    const int bx  = blockIdx.x;
    const int tid = threadIdx.x;

    if (bx >= LIN_BLOCKS) {
        // ================= phase 1, scatter path =================
        const int sb = bx - LIN_BLOCKS;                    // 0..767
        const int t  = sb * 256 + tid;                     // t < 196608 < E
        const int e1 = t + SCAT_THREADS;
        const bool has1 = (e1 < E_EDGES);
        int er0 = row[t], ec0 = col[t];
        int er1 = 0, ec1 = 0;
        if (has1) { er1 = row[e1]; ec1 = col[e1]; }

        if (sb < NZB) {
            int old = atomicExch(&cursor[sb * 256 + tid], 0);
            asm volatile("" :: "v"(old));
            if (sb == 0 && tid == 0) {
                int oa = atomicExch(c1, 0); asm volatile("" :: "v"(oa));
                int ob = atomicExch(c2, 0); asm volatile("" :: "v"(ob));
            }
            __syncthreads();                   // vmcnt(0): zeros performed at LLC
            if (tid == 0) {
                int o2 = atomicExch(&done[sb * DONE_STRIDE], FLAG_MAGIC);
                asm volatile("" :: "v"(o2));
            }
        }
        // gate: all 32 slices zeroed (also guarantees c1/c2 zeroed)
        if (tid < NZB) {
            while (atomicAdd(&done[tid * DONE_STRIDE], 0) != FLAG_MAGIC)
                __builtin_amdgcn_s_sleep(8);
        }
        __syncthreads();

        int slot = atomicAdd(&cursor[er0], 1);     // final value == degree (dups counted)
        if (slot < CAP) {
            int o = atomicExch(&colbuf[(er0 << 7) + slot], ec0);
            asm volatile("" :: "v"(o));
        }
        if (has1) {
            slot = atomicAdd(&cursor[er1], 1);
            if (slot < CAP) {
                int o = atomicExch(&colbuf[(er1 << 7) + slot], ec1);
                asm volatile("" :: "v"(o));
            }
        }
    } else {
        // ================= phase 1, linear path =================
        const int r0 = bx * 16;
        const int tx = tid & 31;
        const int ty = tid >> 5;

        float acc[2][4];
#pragma unroll
        for (int i = 0; i < 2; ++i)
#pragma unroll
            for (int j = 0; j < 4; ++j) acc[i][j] = 0.0f;

        for (int kc = 0; kc < DIM; kc += 32) {
            {
                int kl = tid & 31;
                int rl = tid >> 5;  // 0..7
                sm.lin.xsT[kl][rl]     = x[(size_t)(r0 + rl) * DIM + kc + kl];
                sm.lin.xsT[kl][rl + 8] = x[(size_t)(r0 + rl + 8) * DIM + kc + kl];
            }
            {
                int o  = tid >> 1;
                int kb = (tid & 1) * 16;
#pragma unroll
                for (int j = 0; j < 4; ++j) {
                    float4 w4 = *(const float4*)&W[(size_t)o * DIM + kc + kb + 4 * j];
                    sm.lin.wsT[kb + 4 * j + 0][o] = w4.x;
                    sm.lin.wsT[kb + 4 * j + 1][o] = w4.y;
                    sm.lin.wsT[kb + 4 * j + 2][o] = w4.z;
                    sm.lin.wsT[kb + 4 * j + 3][o] = w4.w;
                }
            }
            __syncthreads();
#pragma unroll
            for (int k = 0; k < 32; ++k) {
                float a0 = sm.lin.xsT[k][ty * 2];
                float a1 = sm.lin.xsT[k][ty * 2 + 1];
                float4 b4 = *(const float4*)&sm.lin.wsT[k][tx * 4];
                float bb[4] = {b4.x, b4.y, b4.z, b4.w};
#pragma unroll
                for (int j = 0; j < 4; ++j) {
                    acc[0][j] += a0 * bb[j];
                    acc[1][j] += a1 * bb[j];
                }
            }
            __syncthreads();
        }

        float4 bias = *(const float4*)&b[tx * 4];
#pragma unroll
        for (int i = 0; i < 2; ++i) {
            int r = r0 + ty * 2 + i;
            ushort4 o4;
            o4.x = __hip_bfloat16_raw(__float2bfloat16(acc[i][0] + bias.x)).x;
            o4.y = __hip_bfloat16_raw(__float2bfloat16(acc[i][1] + bias.y)).x;
            o4.z = __hip_bfloat16_raw(__float2bfloat16(acc[i][2] + bias.z)).x;
            o4.w = __hip_bfloat16_raw(__float2bfloat16(acc[i][3] + bias.w)).x;
            unsigned long long v =  (unsigned long long)o4.x
                                 | ((unsigned long long)o4.y << 16)
                                 | ((unsigned long long)o4.z << 32)
                                 | ((unsigned long long)o4.w << 48);
            // atomic write -> h lives at the LLC, visible to phase 2 everywhere
            unsigned long long old = atomicExch(
                (unsigned long long*)&h[((size_t)r << 7) + tx * 4], v);
            asm volatile("" :: "v"(old));
        }
        // gate on done-slots (c1 guaranteed zeroed before we touch it);
        // zeroing (~2us) finishes long before linear (~5us): no real wait
        if (tid < NZB) {
            while (atomicAdd(&done[tid * DONE_STRIDE], 0) != FLAG_MAGIC)
                __builtin_amdgcn_s_sleep(8);
        }
    }

    // ============== phase barrier: all 1280 blocks done with phase 1 ==========
    __syncthreads();                           // vmcnt(0): my RMWs performed at LLC
    if (tid == 0) {
        int o = atomicAdd(c1, 1);
        asm volatile("" :: "v"(o));
        while (atomicAdd(c1, 0) < NBLK_TOT) __builtin_amdgcn_s_sleep(8);
    }
    __syncthreads();

    // ================= phase 2: aggregate =================
    // out[r] = relu( sum_{unique c} rsqrt(deg r)*rsqrt(deg c) * h[c] )
    // 5120 teams of 64 lanes; teams 0..3071 take a second row.
    const int team = tid >> 6;     // 0..3
    const int lane = tid & 63;
    const int tg   = (bx << 2) + team;
#pragma unroll 1
    for (int r = tg; r < N_NODES; r += NBLK_TOT * 4) {
#pragma unroll
        for (int j = 0; j < 4; ++j) sm.agg.bitmap[team][lane * 4 + j] = 0u;
        __syncthreads();
        const int dr  = cursor[r];             // plain load: first read, misses to LLC
        const int cnt = min(dr, CAP);
        const float dinv_r = (dr > 0) ? rsqrtf((float)dr) : 0.0f;
#pragma unroll
        for (int half = 0; half < 2; ++half) {
            int s = lane + 64 * half;
            if (s < cnt) {
                int c = colbuf[(r << 7) + s];
                unsigned int bit = 1u << (c & 31);
                unsigned int old = atomicOr(&sm.agg.bitmap[team][c >> 5], bit);
                int dc = cursor[c];
                float nv = 0.0f;
                if (!(old & bit) && dc > 0) nv = dinv_r * rsqrtf((float)dc);
                sm.agg.klist[team][s] = c;     // uniform load; duplicate weight = 0
                sm.agg.nlist[team][s] = nv;
            }
        }
        __syncthreads();
        float acc0 = 0.0f, acc1 = 0.0f;
        int i = 0;
        for (; i + 8 <= cnt; i += 8) {
#pragma unroll
            for (int j = 0; j < 8; ++j) {
                int   c = sm.agg.klist[team][i + j];
                float n = sm.agg.nlist[team][i + j];
                ushort2 hv = *(const ushort2*)&h[((size_t)c << 7) + lane * 2];
                acc0 += n * __bfloat162float(*(const __hip_bfloat16*)&hv.x);
                acc1 += n * __bfloat162float(*(const __hip_bfloat16*)&hv.y);
            }
        }
        for (; i < cnt; ++i) {
            int   c = sm.agg.klist[team][i];
            float n = sm.agg.nlist[team][i];
            ushort2 hv = *(const ushort2*)&h[((size_t)c << 7) + lane * 2];
            acc0 += n * __bfloat162float(*(const __hip_bfloat16*)&hv.x);
            acc1 += n * __bfloat162float(*(const __hip_bfloat16*)&hv.y);
        }
        float2 o2 = make_float2(fmaxf(acc0, 0.0f), fmaxf(acc1, 0.0f));
        *(float2*)&out[((size_t)r << 7) + lane * 2] = o2;
        __syncthreads();           // protect klist/nlist/bitmap before next row
    }

    // ======== completion accounting: last block resets sync state ========
    if (tid == 0) {
        int old2 = atomicAdd(c2, 1);
        if (old2 == NBLK_TOT - 1) {            // everyone's polls exited long ago
#pragma unroll
            for (int j = 0; j < NZB; ++j) {
                int o = atomicExch(&done[j * DONE_STRIDE], 0);
                asm volatile("" :: "v"(o));
            }
            int oa = atomicExch(c1, 0); asm volatile("" :: "v"(oa));
            int ob = atomicExch(c2, 0); asm volatile("" :: "v"(ob));
        }
    }
}

extern "C" void kernel_launch(void* const* d_in, const int* in_sizes, int n_in,
                              void* d_out, int out_size, void* d_ws, size_t ws_size,
                              hipStream_t stream) {
    const float* x  = (const float*)d_in[0];
    const int*   ei = (const int*)d_in[1];
    const float* W  = (const float*)d_in[2];
    const float* b  = (const float*)d_in[3];
    float* out = (float*)d_out;

    char* ws = (char*)d_ws;
    __hip_bfloat16* h = (__hip_bfloat16*)ws;                          // 2 MB
    int* colbuf = (int*)(ws + (size_t)N_NODES * DIM * 2);             // 4 MB
    int* cursor = colbuf + (size_t)N_NODES * CAP;                     // 32 KB
    int* done   = cursor + N_NODES;                                   // 32 slots + c1 + c2

    const int* row = ei;
    const int* col = ei + E_EDGES;

    gcn_mono<<<NBLK_TOT, 256, 0, stream>>>(row, col, x, W, b,
                                           cursor, colbuf, h, out, done);
}

// Round 14
// 97.024 us; speedup vs baseline: 1.4865x; 1.4865x over previous
//
#include <hip/hip_runtime.h>
#include <hip/hip_bf16.h>

#define N_NODES 8192
#define E_EDGES 262144
#define DIM 128
#define CAP 128                 // colbuf stride; degree ~ Poisson(32), max << 128
#define LIN_BLOCKS 512          // 16 rows each
#define SCAT_BLOCKS 768
#define NBLK_TOT (LIN_BLOCKS + SCAT_BLOCKS)     // 1280
#define SCAT_THREADS (SCAT_BLOCKS * 256)
#define NZB 32                  // zeroing blocks = first 32 scatter blocks
#define DONE_STRIDE 32          // ints between slots (128B, own cacheline)
#define FLAG_MAGIC 0x7F3D5B91   // != 0, != 0xAAAAAAAA (poison)

// SINGLE-DISPATCH GCN layer, v2. R13 lesson added to the R8-R12 rules:
//  - NEVER sustain RMW-polling on ONE line with many waiters (R13: 1280
//    pollers on c1 + real wait time => LLC same-line convoy, 145us idle).
//    Barrier here: one atomicAdd(c1,1) per block (no poll), last arriver
//    broadcasts MAGIC to 32 'go' lines, blocks poll go[bx&31] (40/line).
//  - NO __threadfence (R8-R10: buffer_inv/wbl2 storm, 60-77us).
//  - All cross-block data that must be WRITTEN and then READ within this
//    dispatch goes through LLC atomics. h/cursor plain READS are safe across
//    replays (values bit-identical each call); colbuf slot ORDER is not
//    deterministic, so phase-2 colbuf reads are atomicAdd(p,0) (coherent).
//  - Distributed zeroing (32 blocks), throttled one-shot gates (R12).
// Deadlock-safety: zeroers signal BEFORE any wait; 19.5KB LDS, 256 thr =>
// 8 blocks/CU x 256 CUs = 2048 >= 1280 -> co-resident regardless of order;
// __launch_bounds__(256,5) guarantees >=5 blocks/CU.
__global__ __launch_bounds__(256, 5) void gcn_mono(
        const int* __restrict__ row, const int* __restrict__ col,
        const float* __restrict__ x, const float* __restrict__ W,
        const float* __restrict__ b,
        int* __restrict__ cursor, int* __restrict__ colbuf,
        __hip_bfloat16* __restrict__ h, float* __restrict__ out,
        int* __restrict__ done) {
    __shared__ union {
        struct { float xsT[32][20]; float wsT[32][132]; } lin;               // 19456 B
        struct { unsigned int bitmap[4][N_NODES / 32];
                 int klist[4][CAP]; float nlist[4][CAP]; } agg;              // 8192 B
    } sm;
    int* c1 = done + NZB * DONE_STRIDE;        // own cacheline
    int* c2 = c1 + 32;                         // own cacheline
    int* go = c2 + 32;                         // 32 slots x 128B
    const int bx  = blockIdx.x;
    const int tid = threadIdx.x;

    if (bx >= LIN_BLOCKS) {
        // ================= phase 1, scatter path =================
        const int sb = bx - LIN_BLOCKS;                    // 0..767
        const int t  = sb * 256 + tid;                     // t < 196608 < E
        const int e1 = t + SCAT_THREADS;
        const bool has1 = (e1 < E_EDGES);
        int er0 = row[t], ec0 = col[t];
        int er1 = 0, ec1 = 0;
        if (has1) { er1 = row[e1]; ec1 = col[e1]; }

        if (sb < NZB) {
            int old = atomicExch(&cursor[sb * 256 + tid], 0);
            asm volatile("" :: "v"(old));
            if (sb == 0 && tid < NZB) {        // zero go slots before signaling
                int og = atomicExch(&go[tid * DONE_STRIDE], 0);
                asm volatile("" :: "v"(og));
            }
            if (sb == 0 && tid == 0) {
                int oa = atomicExch(c1, 0); asm volatile("" :: "v"(oa));
                int ob = atomicExch(c2, 0); asm volatile("" :: "v"(ob));
            }
            __syncthreads();                   // vmcnt(0): zeros performed at LLC
            if (tid == 0) {
                int o2 = atomicExch(&done[sb * DONE_STRIDE], FLAG_MAGIC);
                asm volatile("" :: "v"(o2));
            }
        }
        // gate: all 32 slices zeroed (also guarantees go/c1/c2 zeroed).
        // nearly always satisfied on first poll (zeroing ~1us, one-shot).
        if (tid < NZB) {
            while (atomicAdd(&done[tid * DONE_STRIDE], 0) != FLAG_MAGIC)
                __builtin_amdgcn_s_sleep(8);
        }
        __syncthreads();

        int slot = atomicAdd(&cursor[er0], 1);     // final value == degree (dups counted)
        if (slot < CAP) {
            int o = atomicExch(&colbuf[(er0 << 7) + slot], ec0);
            asm volatile("" :: "v"(o));
        }
        if (has1) {
            slot = atomicAdd(&cursor[er1], 1);
            if (slot < CAP) {
                int o = atomicExch(&colbuf[(er1 << 7) + slot], ec1);
                asm volatile("" :: "v"(o));
            }
        }
    } else {
        // ================= phase 1, linear path =================
        const int r0 = bx * 16;
        const int tx = tid & 31;
        const int ty = tid >> 5;

        float acc[2][4];
#pragma unroll
        for (int i = 0; i < 2; ++i)
#pragma unroll
            for (int j = 0; j < 4; ++j) acc[i][j] = 0.0f;

        for (int kc = 0; kc < DIM; kc += 32) {
            {
                int kl = tid & 31;
                int rl = tid >> 5;  // 0..7
                sm.lin.xsT[kl][rl]     = x[(size_t)(r0 + rl) * DIM + kc + kl];
                sm.lin.xsT[kl][rl + 8] = x[(size_t)(r0 + rl + 8) * DIM + kc + kl];
            }
            {
                int o  = tid >> 1;
                int kb = (tid & 1) * 16;
#pragma unroll
                for (int j = 0; j < 4; ++j) {
                    float4 w4 = *(const float4*)&W[(size_t)o * DIM + kc + kb + 4 * j];
                    sm.lin.wsT[kb + 4 * j + 0][o] = w4.x;
                    sm.lin.wsT[kb + 4 * j + 1][o] = w4.y;
                    sm.lin.wsT[kb + 4 * j + 2][o] = w4.z;
                    sm.lin.wsT[kb + 4 * j + 3][o] = w4.w;
                }
            }
            __syncthreads();
#pragma unroll
            for (int k = 0; k < 32; ++k) {
                float a0 = sm.lin.xsT[k][ty * 2];
                float a1 = sm.lin.xsT[k][ty * 2 + 1];
                float4 b4 = *(const float4*)&sm.lin.wsT[k][tx * 4];
                float bb[4] = {b4.x, b4.y, b4.z, b4.w};
#pragma unroll
                for (int j = 0; j < 4; ++j) {
                    acc[0][j] += a0 * bb[j];
                    acc[1][j] += a1 * bb[j];
                }
            }
            __syncthreads();
        }

        float4 bias = *(const float4*)&b[tx * 4];
#pragma unroll
        for (int i = 0; i < 2; ++i) {
            int r = r0 + ty * 2 + i;
            ushort4 o4;
            o4.x = __hip_bfloat16_raw(__float2bfloat16(acc[i][0] + bias.x)).x;
            o4.y = __hip_bfloat16_raw(__float2bfloat16(acc[i][1] + bias.y)).x;
            o4.z = __hip_bfloat16_raw(__float2bfloat16(acc[i][2] + bias.z)).x;
            o4.w = __hip_bfloat16_raw(__float2bfloat16(acc[i][3] + bias.w)).x;
            unsigned long long v =  (unsigned long long)o4.x
                                 | ((unsigned long long)o4.y << 16)
                                 | ((unsigned long long)o4.z << 32)
                                 | ((unsigned long long)o4.w << 48);
            // atomic write -> h lives at the LLC, visible to phase 2 everywhere
            unsigned long long old = atomicExch(
                (unsigned long long*)&h[((size_t)r << 7) + tx * 4], v);
            asm volatile("" :: "v"(old));
        }
        // gate on done-slots (zeroing finished ~1us in: satisfied immediately)
        if (tid < NZB) {
            while (atomicAdd(&done[tid * DONE_STRIDE], 0) != FLAG_MAGIC)
                __builtin_amdgcn_s_sleep(8);
        }
    }

    // ====== phase barrier: one RMW per block + 32-line broadcast (no convoy) ==
    __syncthreads();                           // vmcnt(0): my RMWs performed at LLC
    if (tid == 0) {
        int old = atomicAdd(c1, 1);
        if (old == NBLK_TOT - 1) {             // last arriver broadcasts
#pragma unroll
            for (int j = 0; j < 32; ++j) {
                int o = atomicExch(&go[j * DONE_STRIDE], FLAG_MAGIC);
                asm volatile("" :: "v"(o));
            }
        }
        while (atomicAdd(&go[(bx & 31) * DONE_STRIDE], 0) != FLAG_MAGIC)
            __builtin_amdgcn_s_sleep(16);      // ~40 throttled pollers per line
    }
    __syncthreads();

    // ================= phase 2: aggregate =================
    // out[r] = relu( sum_{unique c} rsqrt(deg r)*rsqrt(deg c) * h[c] )
    const int team = tid >> 6;     // 0..3
    const int lane = tid & 63;
    const int tg   = (bx << 2) + team;
#pragma unroll 1
    for (int r = tg; r < N_NODES; r += NBLK_TOT * 4) {
#pragma unroll
        for (int j = 0; j < 4; ++j) sm.agg.bitmap[team][lane + 64 * j] = 0u;  // conflict-free init
        __syncthreads();
        const int dr  = cursor[r];             // plain: deg identical every replay
        const int cnt = min(dr, CAP);
        const float dinv_r = (dr > 0) ? rsqrtf((float)dr) : 0.0f;
#pragma unroll
        for (int half = 0; half < 2; ++half) {
            int s = lane + 64 * half;
            if (s < cnt) {
                // ATOMIC read: colbuf slot order differs across replays; stale
                // remote-L2 lines would mix permutations -> must read at LLC.
                int c = atomicAdd(&colbuf[(r << 7) + s], 0);
                unsigned int bit = 1u << (c & 31);
                unsigned int old = atomicOr(&sm.agg.bitmap[team][c >> 5], bit);
                int dc = cursor[c];            // plain: identical every replay
                float nv = 0.0f;
                if (!(old & bit) && dc > 0) nv = dinv_r * rsqrtf((float)dc);
                sm.agg.klist[team][s] = c;     // uniform load; duplicate weight = 0
                sm.agg.nlist[team][s] = nv;
            }
        }
        __syncthreads();
        float acc0 = 0.0f, acc1 = 0.0f;
        int i = 0;
        for (; i + 8 <= cnt; i += 8) {
#pragma unroll
            for (int j = 0; j < 8; ++j) {
                int   c = sm.agg.klist[team][i + j];
                float n = sm.agg.nlist[team][i + j];
                ushort2 hv = *(const ushort2*)&h[((size_t)c << 7) + lane * 2];
                acc0 += n * __bfloat162float(*(const __hip_bfloat16*)&hv.x);
                acc1 += n * __bfloat162float(*(const __hip_bfloat16*)&hv.y);
            }
        }
        for (; i < cnt; ++i) {
            int   c = sm.agg.klist[team][i];
            float n = sm.agg.nlist[team][i];
            ushort2 hv = *(const ushort2*)&h[((size_t)c << 7) + lane * 2];
            acc0 += n * __bfloat162float(*(const __hip_bfloat16*)&hv.x);
            acc1 += n * __bfloat162float(*(const __hip_bfloat16*)&hv.y);
        }
        float2 o2 = make_float2(fmaxf(acc0, 0.0f), fmaxf(acc1, 0.0f));
        *(float2*)&out[((size_t)r << 7) + lane * 2] = o2;
        __syncthreads();           // protect klist/nlist/bitmap before next row
    }

    // ======== completion accounting: last block resets sync state ========
    if (tid == 0) {
        int old2 = atomicAdd(c2, 1);
        if (old2 == NBLK_TOT - 1) {            // everyone's polls exited long ago
#pragma unroll
            for (int j = 0; j < NZB; ++j) {
                int o = atomicExch(&done[j * DONE_STRIDE], 0);
                asm volatile("" :: "v"(o));
                int g = atomicExch(&go[j * DONE_STRIDE], 0);
                asm volatile("" :: "v"(g));
            }
            int oa = atomicExch(c1, 0); asm volatile("" :: "v"(oa));
            int ob = atomicExch(c2, 0); asm volatile("" :: "v"(ob));
        }
    }
}

extern "C" void kernel_launch(void* const* d_in, const int* in_sizes, int n_in,
                              void* d_out, int out_size, void* d_ws, size_t ws_size,
                              hipStream_t stream) {
    const float* x  = (const float*)d_in[0];
    const int*   ei = (const int*)d_in[1];
    const float* W  = (const float*)d_in[2];
    const float* b  = (const float*)d_in[3];
    float* out = (float*)d_out;

    char* ws = (char*)d_ws;
    __hip_bfloat16* h = (__hip_bfloat16*)ws;                          // 2 MB
    int* colbuf = (int*)(ws + (size_t)N_NODES * DIM * 2);             // 4 MB
    int* cursor = colbuf + (size_t)N_NODES * CAP;                     // 32 KB
    int* done   = cursor + N_NODES;                                   // done/c1/c2/go

    const int* row = ei;
    const int* col = ei + E_EDGES;

    gcn_mono<<<NBLK_TOT, 256, 0, stream>>>(row, col, x, W, b,
                                           cursor, colbuf, h, out, done);
}

// Round 15
// 32.178 us; speedup vs baseline: 4.4822x; 3.0152x over previous
//
#include <hip/hip_runtime.h>
#include <hip/hip_bf16.h>

#define N_NODES 8192
#define E_EDGES 262144
#define DIM 128
#define CAP 128                 // colbuf stride; degree ~ Poisson(32), max << 128
#define LIN_BLOCKS 512          // 16 rows each
#define SCAT_BLOCKS 768
#define SCAT_THREADS (SCAT_BLOCKS * 256)
#define NZB 32                  // zeroing blocks = first 32 scatter blocks
#define DONE_STRIDE 32          // ints between done slots (128B, own cacheline)
#define FLAG_MAGIC 0x7F3D5B91   // != 0, != 0xAAAAAAAA (poison)

// 2-dispatch structure (R12, 30.8us) -- proven floor architecture. R13/R14
// showed single-dispatch fusion cannot win: intra-kernel cross-XCD visibility
// costs 50us+ in any form (fences = L2-inv storms; LLC-RMW data movement =
// atomic serialization; barriers = poll convoys). The kernel boundary is the
// cheapest coherence operation on this chip.
// Fence-free handshake rules (R8-R12): no __threadfence; sync via atomic RMWs
// at the LLC; distributed zeroing; one-shot throttled polls on spread lines.
__global__ __launch_bounds__(256) void fused_scatter_linear(
        const int* __restrict__ row, const int* __restrict__ col,
        int* __restrict__ cursor, unsigned short* __restrict__ colbuf,
        const float* __restrict__ x, const float* __restrict__ W,
        const float* __restrict__ b, __hip_bfloat16* __restrict__ h,
        int* __restrict__ done) {
    __shared__ float xsT[32][20];    // [k_local][row_local], padded
    __shared__ float wsT[32][132];   // [k_local][o], padded
    const int bx  = blockIdx.x;
    const int tid = threadIdx.x;

    if (bx >= LIN_BLOCKS) {
        // ---- scatter path ----
        const int sb = bx - LIN_BLOCKS;                    // 0..767
        const int t  = sb * 256 + tid;                     // t < 196608 < E
        const int e1 = t + SCAT_THREADS;
        const bool has1 = (e1 < E_EDGES);
        int r0 = row[t], c0 = col[t];
        int r1 = 0, c1 = 0;
        if (has1) { r1 = row[e1]; c1 = col[e1]; }

        if (sb < NZB) {
            // zero my 256-word slice of cursor (one RMW per thread, parallel)
            int old = atomicExch(&cursor[sb * 256 + tid], 0);
            asm volatile("" :: "v"(old));      // returning form; vmcnt tracks it
            __syncthreads();                   // waitcnt vmcnt(0): zeros performed
            if (tid == 0) {
                int o2 = atomicExch(&done[sb * DONE_STRIDE], FLAG_MAGIC);
                asm volatile("" :: "v"(o2));
            }
        }

        // wait for all 32 slices: threads 0..31 poll one slot each (RMW at LLC)
        if (tid < NZB) {
            while (atomicAdd(&done[tid * DONE_STRIDE], 0) != FLAG_MAGIC) {
                __builtin_amdgcn_s_sleep(8);
            }
        }
        __syncthreads();       // control gate; no fence needed (next access is RMW)

        int slot = atomicAdd(&cursor[r0], 1);      // final value == degree (dups counted)
        if (slot < CAP) colbuf[(r0 << 7) + slot] = (unsigned short)c0;
        if (has1) {
            slot = atomicAdd(&cursor[r1], 1);
            if (slot < CAP) colbuf[(r1 << 7) + slot] = (unsigned short)c1;
        }
        return;
    }

    // ---- linear path: 512 blocks, 16 rows each, 2x4 micro-tile ----
    const int r0 = bx * 16;
    const int tx = tid & 31;   // col group: cols tx*4 .. tx*4+3
    const int ty = tid >> 5;   // row group: rows ty*2 .. ty*2+1

    float acc[2][4];
#pragma unroll
    for (int i = 0; i < 2; ++i)
#pragma unroll
        for (int j = 0; j < 4; ++j) acc[i][j] = 0.0f;

    for (int kc = 0; kc < DIM; kc += 32) {
        {
            int kl = tid & 31;
            int rl = tid >> 5;  // 0..7
            xsT[kl][rl]     = x[(size_t)(r0 + rl) * DIM + kc + kl];
            xsT[kl][rl + 8] = x[(size_t)(r0 + rl + 8) * DIM + kc + kl];
        }
        {
            int o  = tid >> 1;            // 0..127
            int kb = (tid & 1) * 16;      // 0 or 16
#pragma unroll
            for (int j = 0; j < 4; ++j) {
                float4 w4 = *(const float4*)&W[(size_t)o * DIM + kc + kb + 4 * j];
                wsT[kb + 4 * j + 0][o] = w4.x;
                wsT[kb + 4 * j + 1][o] = w4.y;
                wsT[kb + 4 * j + 2][o] = w4.z;
                wsT[kb + 4 * j + 3][o] = w4.w;
            }
        }
        __syncthreads();
#pragma unroll
        for (int k = 0; k < 32; ++k) {
            float a0 = xsT[k][ty * 2];
            float a1 = xsT[k][ty * 2 + 1];
            float4 b4 = *(const float4*)&wsT[k][tx * 4];
            float bb[4] = {b4.x, b4.y, b4.z, b4.w};
#pragma unroll
            for (int j = 0; j < 4; ++j) {
                acc[0][j] += a0 * bb[j];
                acc[1][j] += a1 * bb[j];
            }
        }
        __syncthreads();
    }

    float4 bias = *(const float4*)&b[tx * 4];
#pragma unroll
    for (int i = 0; i < 2; ++i) {
        int r = r0 + ty * 2 + i;
        ushort4 o4;
        o4.x = __hip_bfloat16_raw(__float2bfloat16(acc[i][0] + bias.x)).x;
        o4.y = __hip_bfloat16_raw(__float2bfloat16(acc[i][1] + bias.y)).x;
        o4.z = __hip_bfloat16_raw(__float2bfloat16(acc[i][2] + bias.z)).x;
        o4.w = __hip_bfloat16_raw(__float2bfloat16(acc[i][3] + bias.w)).x;
        *(ushort4*)&h[((size_t)r << 7) + tx * 4] = o4;
    }
}

// out[r] = relu( sum_{unique c in adj(r)} rsqrt(deg[r])*rsqrt(deg[c]) * h[c] )
// 2048 blocks x 256 threads: 4 teams of 64 lanes = 4 WAVES, 1 row per team.
// R14 counter lesson: the LDS atomicOr bitmap dedup cost ~6.7M bank-conflict
// cycles (random-address bank atomics, ~8-way). Teams are single waves and
// klist/nlist are team-private, so dedup is a wave-local klist scan (LDS
// broadcast reads, conflict-free) and NO __syncthreads is needed anywhere.
__global__ __launch_bounds__(256) void aggregate_kernel(
        const int* __restrict__ deg, const unsigned short* __restrict__ colbuf,
        const __hip_bfloat16* __restrict__ h, float* __restrict__ out,
        int* __restrict__ done) {
    __shared__ int   klist[4][CAP];
    __shared__ float nlist[4][CAP];
    const int bx   = blockIdx.x;
    const int tid  = threadIdx.x;
    const int team = tid >> 6;     // 0..3 (= wave id)
    const int lane = tid & 63;
    const int r    = (bx << 2) + team;

    if (bx == 0 && tid < NZB) atomicExch(&done[tid * DONE_STRIDE], 0);  // re-arm

    const int dr  = deg[r];
    const int cnt = min(dr, CAP);
    const float dinv_r = (dr > 0) ? rsqrtf((float)dr) : 0.0f;

    // stage neighbor ids into wave-private klist
#pragma unroll
    for (int half = 0; half < 2; ++half) {
        int s = lane + 64 * half;
        if (s < cnt) klist[team][s] = colbuf[(r << 7) + s];
    }
    __builtin_amdgcn_wave_barrier();   // DS ops of one wave are in-order; this
                                       // just stops compiler reordering

    // dedup scan + norm: lane s is a dup iff any t<s holds the same id.
    // LDS reads here are same-word broadcasts across lanes -> conflict-free.
#pragma unroll
    for (int half = 0; half < 2; ++half) {
        int s = lane + 64 * half;
        if (s < cnt) {
            int c = klist[team][s];
            bool dup = false;
            for (int t = 0; t < s; ++t) dup |= (klist[team][t] == c);
            int dc = deg[c];               // 32KB array -> cache-resident
            float nv = 0.0f;
            if (!dup && dc > 0) nv = dinv_r * rsqrtf((float)dc);
            nlist[team][s] = nv;           // duplicate weight = 0 (uniform gather)
        }
    }
    __builtin_amdgcn_wave_barrier();

    // gather: lane owns dims (2*lane, 2*lane+1); klist/nlist reads broadcast
    float acc0 = 0.0f, acc1 = 0.0f;
    int i = 0;
    for (; i + 8 <= cnt; i += 8) {
#pragma unroll
        for (int j = 0; j < 8; ++j) {
            int   c = klist[team][i + j];
            float n = nlist[team][i + j];
            ushort2 hv = *(const ushort2*)&h[((size_t)c << 7) + lane * 2];
            acc0 += n * __bfloat162float(*(const __hip_bfloat16*)&hv.x);
            acc1 += n * __bfloat162float(*(const __hip_bfloat16*)&hv.y);
        }
    }
    for (; i < cnt; ++i) {
        int   c = klist[team][i];
        float n = nlist[team][i];
        ushort2 hv = *(const ushort2*)&h[((size_t)c << 7) + lane * 2];
        acc0 += n * __bfloat162float(*(const __hip_bfloat16*)&hv.x);
        acc1 += n * __bfloat162float(*(const __hip_bfloat16*)&hv.y);
    }

    float2 o2 = make_float2(fmaxf(acc0, 0.0f), fmaxf(acc1, 0.0f));
    *(float2*)&out[((size_t)r << 7) + lane * 2] = o2;
}

extern "C" void kernel_launch(void* const* d_in, const int* in_sizes, int n_in,
                              void* d_out, int out_size, void* d_ws, size_t ws_size,
                              hipStream_t stream) {
    const float* x  = (const float*)d_in[0];
    const int*   ei = (const int*)d_in[1];
    const float* W  = (const float*)d_in[2];
    const float* b  = (const float*)d_in[3];
    float* out = (float*)d_out;

    char* ws = (char*)d_ws;
    __hip_bfloat16* h = (__hip_bfloat16*)ws;                                     // 2 MB
    unsigned short* colbuf = (unsigned short*)(ws + (size_t)N_NODES * DIM * 2);  // 2 MB
    int* cursor = (int*)(ws + (size_t)N_NODES * DIM * 2 + (size_t)N_NODES * CAP * 2); // 32 KB
    int* done   = cursor + N_NODES;                                              // 32 slots x 128B

    const int* row = ei;
    const int* col = ei + E_EDGES;

    fused_scatter_linear<<<LIN_BLOCKS + SCAT_BLOCKS, 256, 0, stream>>>(
        row, col, cursor, colbuf, x, W, b, h, done);
    aggregate_kernel<<<N_NODES / 4, 256, 0, stream>>>(cursor, colbuf, h, out, done);
}

// Round 16
// 30.835 us; speedup vs baseline: 4.6775x; 1.0436x over previous
//
#include <hip/hip_runtime.h>
#include <hip/hip_bf16.h>

#define N_NODES 8192
#define E_EDGES 262144
#define DIM 128
#define CAP 128                 // colbuf stride; degree ~ Poisson(32), max << 128
#define LIN_BLOCKS 512          // 16 rows each
#define SCAT_BLOCKS 768
#define SCAT_THREADS (SCAT_BLOCKS * 256)
#define NZB 32                  // zeroing blocks = first 32 scatter blocks
#define DONE_STRIDE 32          // ints between done slots (128B, own cacheline)
#define FLAG_MAGIC 0x7F3D5B91   // != 0, != 0xAAAAAAAA (poison)

// EXACT revert to the R12 kernel (proven 30.8us) -- the session optimum.
// Architecture rationale (R8-R15):
//  - 2 dispatches is the floor: intra-kernel cross-XCD visibility costs 50us+
//    in any form (fences = L2-inv storms R8-R10; LLC-RMW data movement R14;
//    barrier poll convoys R13). Kernel boundary = cheapest coherence op.
//  - Fence-free handshake: no __threadfence; all sync via atomic RMWs at the
//    LLC; distributed zeroing (32 blocks); one-shot throttled polls on 32
//    spread cachelines.
//  - Aggregate: bitmap dedup (R15 showed wave-local scan dedup is no better;
//    gather is latency-bound, LDS conflicts are hidden).
__global__ __launch_bounds__(256) void fused_scatter_linear(
        const int* __restrict__ row, const int* __restrict__ col,
        int* __restrict__ cursor, unsigned short* __restrict__ colbuf,
        const float* __restrict__ x, const float* __restrict__ W,
        const float* __restrict__ b, __hip_bfloat16* __restrict__ h,
        int* __restrict__ done) {
    __shared__ float xsT[32][20];    // [k_local][row_local], padded
    __shared__ float wsT[32][132];   // [k_local][o], padded
    const int bx  = blockIdx.x;
    const int tid = threadIdx.x;

    if (bx >= LIN_BLOCKS) {
        // ---- scatter path ----
        const int sb = bx - LIN_BLOCKS;                    // 0..767
        // prefetch edge data (independent of cursor) before the wait
        const int t  = sb * 256 + tid;                     // t < 196608 < E
        const int e1 = t + SCAT_THREADS;
        const bool has1 = (e1 < E_EDGES);
        int r0 = row[t], c0 = col[t];
        int r1 = 0, c1 = 0;
        if (has1) { r1 = row[e1]; c1 = col[e1]; }

        if (sb < NZB) {
            // zero my 256-word slice of cursor (one RMW per thread, parallel)
            int old = atomicExch(&cursor[sb * 256 + tid], 0);
            asm volatile("" :: "v"(old));      // returning form; vmcnt tracks it
            __syncthreads();                   // waitcnt vmcnt(0): zeros performed
            if (tid == 0) {
                int o2 = atomicExch(&done[sb * DONE_STRIDE], FLAG_MAGIC);
                asm volatile("" :: "v"(o2));
            }
        }

        // wait for all 32 slices: threads 0..31 poll one slot each (RMW at LLC)
        if (tid < NZB) {
            while (atomicAdd(&done[tid * DONE_STRIDE], 0) != FLAG_MAGIC) {
                __builtin_amdgcn_s_sleep(8);
            }
        }
        __syncthreads();       // control gate; no fence needed (next access is RMW)

        int slot = atomicAdd(&cursor[r0], 1);      // final value == degree (dups counted)
        if (slot < CAP) colbuf[(r0 << 7) + slot] = (unsigned short)c0;
        if (has1) {
            slot = atomicAdd(&cursor[r1], 1);
            if (slot < CAP) colbuf[(r1 << 7) + slot] = (unsigned short)c1;
        }
        return;
    }

    // ---- linear path: 512 blocks, 16 rows each, 2x4 micro-tile ----
    const int r0 = bx * 16;
    const int tx = tid & 31;   // col group: cols tx*4 .. tx*4+3
    const int ty = tid >> 5;   // row group: rows ty*2 .. ty*2+1

    float acc[2][4];
#pragma unroll
    for (int i = 0; i < 2; ++i)
#pragma unroll
        for (int j = 0; j < 4; ++j) acc[i][j] = 0.0f;

    for (int kc = 0; kc < DIM; kc += 32) {
        {
            int kl = tid & 31;
            int rl = tid >> 5;  // 0..7
            xsT[kl][rl]     = x[(size_t)(r0 + rl) * DIM + kc + kl];
            xsT[kl][rl + 8] = x[(size_t)(r0 + rl + 8) * DIM + kc + kl];
        }
        {
            int o  = tid >> 1;            // 0..127
            int kb = (tid & 1) * 16;      // 0 or 16
#pragma unroll
            for (int j = 0; j < 4; ++j) {
                float4 w4 = *(const float4*)&W[(size_t)o * DIM + kc + kb + 4 * j];
                wsT[kb + 4 * j + 0][o] = w4.x;
                wsT[kb + 4 * j + 1][o] = w4.y;
                wsT[kb + 4 * j + 2][o] = w4.z;
                wsT[kb + 4 * j + 3][o] = w4.w;
            }
        }
        __syncthreads();
#pragma unroll
        for (int k = 0; k < 32; ++k) {
            float a0 = xsT[k][ty * 2];
            float a1 = xsT[k][ty * 2 + 1];
            float4 b4 = *(const float4*)&wsT[k][tx * 4];
            float bb[4] = {b4.x, b4.y, b4.z, b4.w};
#pragma unroll
            for (int j = 0; j < 4; ++j) {
                acc[0][j] += a0 * bb[j];
                acc[1][j] += a1 * bb[j];
            }
        }
        __syncthreads();
    }

    float4 bias = *(const float4*)&b[tx * 4];
#pragma unroll
    for (int i = 0; i < 2; ++i) {
        int r = r0 + ty * 2 + i;
        ushort4 o4;
        o4.x = __hip_bfloat16_raw(__float2bfloat16(acc[i][0] + bias.x)).x;
        o4.y = __hip_bfloat16_raw(__float2bfloat16(acc[i][1] + bias.y)).x;
        o4.z = __hip_bfloat16_raw(__float2bfloat16(acc[i][2] + bias.z)).x;
        o4.w = __hip_bfloat16_raw(__float2bfloat16(acc[i][3] + bias.w)).x;
        *(ushort4*)&h[((size_t)r << 7) + tx * 4] = o4;
    }
}

// out[r] = relu( sum_{unique c in adj(r)} rsqrt(deg[r])*rsqrt(deg[c]) * h[c] )
// 2048 blocks x 256 threads: 4 teams of 64 lanes, 1 row per team.
// Each lane owns dims (2*lane, 2*lane+1): ushort2 gathers, float2 store.
__global__ __launch_bounds__(256) void aggregate_kernel(
        const int* __restrict__ deg, const unsigned short* __restrict__ colbuf,
        const __hip_bfloat16* __restrict__ h, float* __restrict__ out,
        int* __restrict__ done) {
    __shared__ unsigned int bitmap[4][N_NODES / 32];  // 4 x 1KB
    __shared__ int   klist[4][CAP];
    __shared__ float nlist[4][CAP];
    const int bx   = blockIdx.x;
    const int tid  = threadIdx.x;
    const int team = tid >> 6;     // 0..3
    const int lane = tid & 63;
    const int r    = (bx << 2) + team;

    if (bx == 0 && tid < NZB) atomicExch(&done[tid * DONE_STRIDE], 0);  // re-arm

#pragma unroll
    for (int j = 0; j < 4; ++j) bitmap[team][lane * 4 + j] = 0u;
    __syncthreads();

    const int dr  = deg[r];
    const int cnt = min(dr, CAP);
    const float dinv_r = (dr > 0) ? rsqrtf((float)dr) : 0.0f;

#pragma unroll
    for (int half = 0; half < 2; ++half) {
        int s = lane + 64 * half;
        if (s < cnt) {
            int c = colbuf[(r << 7) + s];
            unsigned int bit = 1u << (c & 31);
            unsigned int old = atomicOr(&bitmap[team][c >> 5], bit);
            int dc = deg[c];                   // 32KB array -> cache-resident
            float nv = 0.0f;
            if (!(old & bit) && dc > 0) nv = dinv_r * rsqrtf((float)dc);
            klist[team][s] = c;                // uniform later load; duplicate weight = 0
            nlist[team][s] = nv;
        }
    }
    __syncthreads();

    float acc0 = 0.0f, acc1 = 0.0f;
    int i = 0;
    for (; i + 8 <= cnt; i += 8) {
#pragma unroll
        for (int j = 0; j < 8; ++j) {
            int   c = klist[team][i + j];
            float n = nlist[team][i + j];
            ushort2 hv = *(const ushort2*)&h[((size_t)c << 7) + lane * 2];
            acc0 += n * __bfloat162float(*(const __hip_bfloat16*)&hv.x);
            acc1 += n * __bfloat162float(*(const __hip_bfloat16*)&hv.y);
        }
    }
    for (; i < cnt; ++i) {
        int   c = klist[team][i];
        float n = nlist[team][i];
        ushort2 hv = *(const ushort2*)&h[((size_t)c << 7) + lane * 2];
        acc0 += n * __bfloat162float(*(const __hip_bfloat16*)&hv.x);
        acc1 += n * __bfloat162float(*(const __hip_bfloat16*)&hv.y);
    }

    float2 o2 = make_float2(fmaxf(acc0, 0.0f), fmaxf(acc1, 0.0f));
    *(float2*)&out[((size_t)r << 7) + lane * 2] = o2;
}

extern "C" void kernel_launch(void* const* d_in, const int* in_sizes, int n_in,
                              void* d_out, int out_size, void* d_ws, size_t ws_size,
                              hipStream_t stream) {
    const float* x  = (const float*)d_in[0];
    const int*   ei = (const int*)d_in[1];
    const float* W  = (const float*)d_in[2];
    const float* b  = (const float*)d_in[3];
    float* out = (float*)d_out;

    char* ws = (char*)d_ws;
    __hip_bfloat16* h = (__hip_bfloat16*)ws;                                     // 2 MB
    unsigned short* colbuf = (unsigned short*)(ws + (size_t)N_NODES * DIM * 2);  // 2 MB
    int* cursor = (int*)(ws + (size_t)N_NODES * DIM * 2 + (size_t)N_NODES * CAP * 2); // 32 KB
    int* done   = cursor + N_NODES;                                              // 32 slots x 128B

    const int* row = ei;
    const int* col = ei + E_EDGES;

    fused_scatter_linear<<<LIN_BLOCKS + SCAT_BLOCKS, 256, 0, stream>>>(
        row, col, cursor, colbuf, x, W, b, h, done);
    aggregate_kernel<<<N_NODES / 4, 256, 0, stream>>>(cursor, colbuf, h, out, done);
}